// Round 7
// baseline (305.125 us; speedup 1.0000x reference)
//
#include <hip/hip_runtime.h>
#include <stdint.h>

#define DIMD 512
#define BATCH 512
#define KSAMP 10
#define NCLS 8192
#define TREJ 32

typedef __bf16 bf16x8 __attribute__((ext_vector_type(8)));
typedef float f32x4 __attribute__((ext_vector_type(4)));

// ---------------- RNG (counter-based, deterministic) ----------------
__device__ inline uint64_t sm64(uint64_t x) {
  x += 0x9E3779B97F4A7C15ull;
  x = (x ^ (x >> 30)) * 0xBF58476D1CE4E5B9ull;
  x = (x ^ (x >> 27)) * 0x94D049BB133111EBull;
  return x ^ (x >> 31);
}
__device__ inline float u01(uint32_t u) {
  return ((float)u + 0.5f) * 2.3283064365386963e-10f;
}
__device__ inline float normal_from(uint64_t r) {
  float u1 = u01((uint32_t)(r >> 32));
  float u2 = u01((uint32_t)r);
  return sqrtf(-2.0f * __logf(u1)) * __cosf(6.28318530718f * u2);
}
__device__ inline float gamma255(uint64_t& ctr) {
  const float dg = 255.1666667f;
  const float cg = 0.02086730f;
  for (int i = 0; i < 16; i++) {
    uint64_t r = sm64(ctr++);
    float x = normal_from(r);
    float t = fmaf(cg, x, 1.0f);
    if (t <= 0.0f) continue;
    float v3 = t * t * t;
    uint64_t r2 = sm64(ctr++);
    float u3 = u01((uint32_t)(r2 >> 32));
    if (__logf(u3) < 0.5f * x * x + dg * (1.0f - v3 + __logf(v3))) return dg * v3;
  }
  return dg;
}
__device__ inline float wave_sum(float v) {
  #pragma unroll
  for (int o = 32; o > 0; o >>= 1) v += __shfl_down(v, o, 64);
  return __shfl(v, 0, 64);
}
__device__ inline float vmf_logc(float k) {
  float k2 = k * k;
  float sm = sqrtf(65280.25f + k2);
  float sp = sqrtf(65792.25f + k2);
  return 127.75f * (logf(255.5f + sm) + logf(255.5f + sp)) - 0.5f * (sm + sp);
}
__device__ inline unsigned short f2bf(float f) {
  uint32_t u = __float_as_uint(f);
  uint32_t r = (u + 0x7FFFu + ((u >> 16) & 1u)) >> 16;
  return (unsigned short)r;
}
__device__ inline float bf2f(unsigned short s) {
  return __uint_as_float(((uint32_t)s) << 16);
}

// ---------------- fused prep (blocks 0..8191) + sample (blocks 8192..9471) ----
__global__ __launch_bounds__(256) void prep_sample(const float* __restrict__ weight,
                                                   const float* __restrict__ params,
                                                   const float* __restrict__ lscale,
                                                   unsigned short* __restrict__ muWb,
                                                   float4* __restrict__ cparams,
                                                   float* __restrict__ rowsum,
                                                   float4* __restrict__ out4,
                                                   unsigned short* __restrict__ Sb) {
  __shared__ float red[4];
  int blk = blockIdx.x, tid = threadIdx.x;
  if (blk < NCLS) {
    int c = blk;
    if (tid < 128) out4[(size_t)c * 128 + tid] = make_float4(0.f, 0.f, 0.f, 0.f);
    if (c < 20) rowsum[c * 256 + tid] = 0.0f;   // 20*256 = 5120

    const float* wr = weight + (size_t)c * (DIMD + 2) + 1;
    float v0 = wr[tid], v1 = wr[tid + 256];
    float s = wave_sum(v0 * v0 + v1 * v1);
    if ((tid & 63) == 0) red[tid >> 6] = s;
    __syncthreads();
    float tot = red[0] + red[1] + red[2] + red[3];
    float inv = rsqrtf(tot);
    muWb[(size_t)c * DIMD + tid]       = f2bf(v0 * inv);
    muWb[(size_t)c * DIMD + tid + 256] = f2bf(v1 * inv);
    if (tid == 0) {
      float hik = weight[(size_t)c * (DIMD + 2) + DIMD + 1];
      float kw = expf(-hik);
      float k1 = expf(lscale[0]);
      float lcw = vmf_logc(kw);
      float A2 = fmaf(k1, k1, kw * kw);
      float B2 = 2.0f * k1 * kw;
      // cubic Chebyshev fit of g(cos) = lcw - logc(kk(cos)), err ~1e-4
      const float X0 = 0.9238795f, X1 = 0.3826834f;
      float g0 = lcw - vmf_logc(sqrtf(fmaf(B2,  X0, A2)));
      float g1 = lcw - vmf_logc(sqrtf(fmaf(B2,  X1, A2)));
      float g2 = lcw - vmf_logc(sqrtf(fmaf(B2, -X1, A2)));
      float g3 = lcw - vmf_logc(sqrtf(fmaf(B2, -X0, A2)));
      float b0 = 0.25f * (g0 + g1 + g2 + g3);
      float b1 = 0.5f * (X0 * (g0 - g3) + X1 * (g1 - g2));
      float b2 = 0.5f * 0.7071068f * ((g0 + g3) - (g1 + g2));
      float b3 = 0.5f * (X1 * (g0 - g3) - X0 * (g1 - g2));
      const float L2E = 1.4426950409f;
      cparams[c] = make_float4((b0 - b2) * L2E, (b1 - 3.0f * b3) * L2E,
                               (2.0f * b2) * L2E, (4.0f * b3) * L2E);
    }
  } else {
    int wave = tid >> 6, lane = tid & 63;
    int row = (blk - NCLS) * 4 + wave;      // b*KSAMP + k
    int b = row / KSAMP;
    const float* pr = params + (size_t)b * (DIMD + 2) + 1;

    float mu[8];
    float n2 = 0.0f;
    #pragma unroll
    for (int j = 0; j < 8; j++) { mu[j] = pr[j * 64 + lane]; n2 += mu[j] * mu[j]; }
    n2 = wave_sum(n2);
    float invn = rsqrtf(n2);
    #pragma unroll
    for (int j = 0; j < 8; j++) mu[j] *= invn;

    float kap = __expf(-pr[DIMD]);
    float bb = (-2.0f * kap + sqrtf(fmaf(4.0f * kap, kap, 511.0f * 511.0f))) / 511.0f;
    float x0 = (1.0f - bb) / (1.0f + bb);
    float cc = kap * x0 + 511.0f * __logf(1.0f - x0 * x0);

    uint64_t ctr = (((uint64_t)(row + 1)) << 32) | ((uint64_t)lane << 8);
    float g1 = gamma255(ctr);
    float g2 = gamma255(ctr);
    float z = g1 / (g1 + g2);
    float wt = (1.0f - (1.0f + bb) * z) / (1.0f - (1.0f - bb) * z);
    uint64_t r = sm64(ctr++);
    float u = u01((uint32_t)(r >> 32));
    float lhs = kap * wt + 511.0f * __logf(1.0f - x0 * wt) - cc;
    bool acc = (lane < TREJ) && (lhs >= __logf(fmaxf(u, 1e-10f)));
    uint64_t mask = __ballot(acc);
    int sel = mask ? (__ffsll((unsigned long long)mask) - 1) : 0;
    float w = __shfl(wt, sel, 64);

    uint64_t cbase = (((uint64_t)(row + 1)) << 32) | 0x40000000ull;
    float v[8];
    #pragma unroll
    for (int j = 0; j < 8; j++) v[j] = normal_from(sm64(cbase + (uint64_t)(j * 64 + lane)));
    float d = 0.0f;
    #pragma unroll
    for (int j = 0; j < 8; j++) d += v[j] * mu[j];
    d = wave_sum(d);
    float t2 = 0.0f;
    #pragma unroll
    for (int j = 0; j < 8; j++) { v[j] -= d * mu[j]; t2 += v[j] * v[j]; }
    t2 = wave_sum(t2);
    float ivt = rsqrtf(t2);
    float st = sqrtf(fmaxf(0.0f, 1.0f - w * w)) * ivt;
    float sv[8];
    float s2 = 0.0f;
    #pragma unroll
    for (int j = 0; j < 8; j++) { sv[j] = fmaf(st, v[j], w * mu[j]); s2 += sv[j] * sv[j]; }
    s2 = wave_sum(s2);
    float is = rsqrtf(s2);
    #pragma unroll
    for (int j = 0; j < 8; j++) Sb[(size_t)row * DIMD + j * 64 + lane] = f2bf(sv[j] * is);
  }
}

// MFMA GEMM (bf16, 128x128, BK=32). Depth-2 REGISTER pipeline:
// buffer_load -> VGPR (chunks i+1,i+2 in flight ACROSS barriers; no global
// stores in-loop so __syncthreads drains only lgkmcnt) -> ds_write -> MFMA.
// XCD swizzle: id&7 = XCD owns an 8-coltile stripe (1 MB of W, L2-resident).
// LDS layout identical to verified one: slot s of row r holds k-group
// s ^ ((r>>1)&3); frag reads 0-conflict, ds_writes <=2-way (free).
__global__ __launch_bounds__(256, 3) void gemm_lse(const unsigned short* __restrict__ Sb,
                                                   const unsigned short* __restrict__ Wb,
                                                   const float4* __restrict__ cparams,
                                                   float* __restrict__ rowsum) {
  __shared__ __align__(16) unsigned short As[2][128 * 32];
  __shared__ __align__(16) unsigned short Bs[2][128 * 32];
  int tid = threadIdx.x;
  int lane = tid & 63, wave = tid >> 6;
  int wm = wave >> 1, wn = wave & 1;
  int tx = lane & 15, tz = lane >> 4;

  int id = blockIdx.x;
  int xcd = id & 7, lid = id >> 3;           // 320 blocks per XCD
  int c0 = (xcd * 8 + (lid & 7)) * 128;      // 8-coltile stripe per XCD
  int r0 = (lid >> 3) * 128;                 // sweep 40 row tiles

  // staging: lane stages 32B of one row of A and one row of B per chunk
  int srow = wave * 32 + (lane >> 1);        // 0..127
  int h = lane & 1;
  int m = (srow >> 1) & 3;
  int kg0 = (2 * h) ^ m, kg1 = (2 * h + 1) ^ m;  // global k-groups for slots 2h,2h+1
  const unsigned short* gA = &Sb[(size_t)(r0 + srow) * DIMD];
  const unsigned short* gB = &Wb[(size_t)(c0 + srow) * DIMD];

  f32x4 acc[4][4];
  #pragma unroll
  for (int i = 0; i < 4; i++)
    #pragma unroll
    for (int j = 0; j < 4; j++) acc[i][j] = (f32x4){0.f, 0.f, 0.f, 0.f};

  int4 ga[2][2], gb[2][2];
  // prologue: load chunks 0,1 into sets 0,1
  #pragma unroll
  for (int s = 0; s < 2; s++) {
    const int4* pa = (const int4*)(gA + s * 32);
    const int4* pb = (const int4*)(gB + s * 32);
    ga[s][0] = pa[kg0]; ga[s][1] = pa[kg1];
    gb[s][0] = pb[kg0]; gb[s][1] = pb[kg1];
  }
  // write chunk 0 into buf 0
  {
    int4* la = (int4*)&As[0][srow * 32];
    int4* lb = (int4*)&Bs[0][srow * 32];
    la[2 * h] = ga[0][0]; la[2 * h + 1] = ga[0][1];
    lb[2 * h] = gb[0][0]; lb[2 * h + 1] = gb[0][1];
  }
  // refill set 0 with chunk 2
  {
    const int4* pa = (const int4*)(gA + 2 * 32);
    const int4* pb = (const int4*)(gB + 2 * 32);
    ga[0][0] = pa[kg0]; ga[0][1] = pa[kg1];
    gb[0][0] = pb[kg0]; gb[0][1] = pb[kg1];
  }
  __syncthreads();

  int p = 0;
  #pragma unroll 2
  for (int it = 0; it < 16; it++) {
    // buf[p] holds chunk it; set[(it+1)&1] holds chunk it+1 (in flight)
    if (it + 1 < 16) {
      int s = (it + 1) & 1;
      int4* la = (int4*)&As[p ^ 1][srow * 32];
      int4* lb = (int4*)&Bs[p ^ 1][srow * 32];
      la[2 * h] = ga[s][0]; la[2 * h + 1] = ga[s][1];   // waits vmcnt(partial)
      lb[2 * h] = gb[s][0]; lb[2 * h + 1] = gb[s][1];
      if (it + 3 < 16) {
        const int4* pa = (const int4*)(gA + (it + 3) * 32);
        const int4* pb = (const int4*)(gB + (it + 3) * 32);
        ga[s][0] = pa[kg0]; ga[s][1] = pa[kg1];
        gb[s][0] = pb[kg0]; gb[s][1] = pb[kg1];
      }
    }
    bf16x8 af[4], bf[4];
    int sA = tz ^ ((tx >> 1) & 3);
    #pragma unroll
    for (int mi = 0; mi < 4; mi++) {
      int rA = wm * 64 + mi * 16 + tx;
      af[mi] = *(const bf16x8*)&As[p][rA * 32 + sA * 8];
      int rB = wn * 64 + mi * 16 + tx;
      bf[mi] = *(const bf16x8*)&Bs[p][rB * 32 + sA * 8];
    }
    #pragma unroll
    for (int mi = 0; mi < 4; mi++)
      #pragma unroll
      for (int ni = 0; ni < 4; ni++)
        acc[mi][ni] = __builtin_amdgcn_mfma_f32_16x16x32_bf16(af[mi], bf[ni], acc[mi][ni], 0, 0, 0);
    __syncthreads();
    p ^= 1;
  }

  // epilogue: s += 2^(cubic(cos)) per class
  float4 cp[4];
  #pragma unroll
  for (int ni = 0; ni < 4; ni++) cp[ni] = cparams[c0 + wn * 64 + ni * 16 + tx];

  #pragma unroll
  for (int mi = 0; mi < 4; mi++) {
    #pragma unroll
    for (int reg = 0; reg < 4; reg++) {
      float s = 0.0f;
      #pragma unroll
      for (int ni = 0; ni < 4; ni++) {
        float cv = acc[mi][ni][reg];
        float g = fmaf(fmaf(fmaf(cp[ni].w, cv, cp[ni].z), cv, cp[ni].y), cv, cp[ni].x);
        s += exp2f(g);
      }
      #pragma unroll
      for (int o = 1; o < 16; o <<= 1) s += __shfl_xor(s, o, 64);
      if (tx == 0)
        atomicAdd(&rowsum[r0 + wm * 64 + mi * 16 + tz * 4 + reg], s);
    }
  }
}

// finalize: renormalizes mu_x from params directly
__global__ __launch_bounds__(64) void finalize_kernel(const float* __restrict__ params,
                                                      const unsigned short* __restrict__ muWb,
                                                      const float* __restrict__ rowsum,
                                                      const int* __restrict__ labels,
                                                      const float* __restrict__ lscale,
                                                      float* __restrict__ out) {
  int b = blockIdx.x;
  int lane = threadIdx.x;
  int lab = labels[b];
  const float* pr = params + (size_t)b * (DIMD + 2) + 1;
  float xv[8];
  float n2 = 0.0f;
  #pragma unroll
  for (int j = 0; j < 8; j++) { xv[j] = pr[j * 64 + lane]; n2 += xv[j] * xv[j]; }
  n2 = wave_sum(n2);
  float invn = rsqrtf(n2);
  float d = 0.0f;
  #pragma unroll
  for (int j = 0; j < 8; j++)
    d += xv[j] * invn * bf2f(muWb[(size_t)lab * DIMD + j * 64 + lane]);
  d = wave_sum(d);
  if (lane == 0) {
    float k1 = expf(lscale[0]);
    float acc = 0.0f;
    #pragma unroll
    for (int k = 0; k < KSAMP; k++) acc += __logf(rowsum[b * KSAMP + k]);
    float loss = acc * (1.0f / KSAMP) - k1 * d;
    out[(size_t)b * NCLS + lab] = -loss;
  }
}

// ---------------- launch ----------------
extern "C" void kernel_launch(void* const* d_in, const int* in_sizes, int n_in,
                              void* d_out, int out_size, void* d_ws, size_t ws_size,
                              hipStream_t stream) {
  const float* params = (const float*)d_in[0];
  const float* weight = (const float*)d_in[1];
  const float* lscale = (const float*)d_in[2];
  const int*   labels = (const int*)d_in[3];
  float* out = (float*)d_out;
  char* ws = (char*)d_ws;

  unsigned short* muWb   = (unsigned short*)(ws);                   // 8192*512*2  = 8,388,608
  unsigned short* Sb     = (unsigned short*)(ws + 8388608);         // 5120*512*2  = 5,242,880
  float4*         cparams= (float4*)(ws + 13631488);                // 8192*16     =   131,072
  float*          rowsum = (float*)(ws + 13762560);                 // 5120*4      =    20,480

  hipLaunchKernelGGL(prep_sample, dim3(NCLS + BATCH * KSAMP / 4), dim3(256), 0, stream,
                     weight, params, lscale, muWb, cparams, rowsum, (float4*)out, Sb);
  hipLaunchKernelGGL(gemm_lse, dim3((NCLS / 128) * (BATCH * KSAMP / 128)), dim3(256), 0, stream,
                     Sb, muWb, cparams, rowsum);
  hipLaunchKernelGGL(finalize_kernel, dim3(BATCH), dim3(64), 0, stream,
                     params, muWb, rowsum, labels, lscale, out);
}

// Round 8
// 168.939 us; speedup vs baseline: 1.8061x; 1.8061x over previous
//
#include <hip/hip_runtime.h>
#include <stdint.h>

#define DIMD 512
#define BATCH 512
#define KSAMP 10
#define NCLS 8192
#define TREJ 32

typedef __bf16 bf16x8 __attribute__((ext_vector_type(8)));
typedef float f32x4 __attribute__((ext_vector_type(4)));

// ---------------- RNG (counter-based, deterministic) ----------------
__device__ inline uint64_t sm64(uint64_t x) {
  x += 0x9E3779B97F4A7C15ull;
  x = (x ^ (x >> 30)) * 0xBF58476D1CE4E5B9ull;
  x = (x ^ (x >> 27)) * 0x94D049BB133111EBull;
  return x ^ (x >> 31);
}
__device__ inline float u01(uint32_t u) {
  return ((float)u + 0.5f) * 2.3283064365386963e-10f;
}
__device__ inline float normal_from(uint64_t r) {
  float u1 = u01((uint32_t)(r >> 32));
  float u2 = u01((uint32_t)r);
  return sqrtf(-2.0f * __logf(u1)) * __cosf(6.28318530718f * u2);
}
__device__ inline float gamma255(uint64_t& ctr) {
  const float dg = 255.1666667f;
  const float cg = 0.02086730f;
  for (int i = 0; i < 16; i++) {
    uint64_t r = sm64(ctr++);
    float x = normal_from(r);
    float t = fmaf(cg, x, 1.0f);
    if (t <= 0.0f) continue;
    float v3 = t * t * t;
    uint64_t r2 = sm64(ctr++);
    float u3 = u01((uint32_t)(r2 >> 32));
    if (__logf(u3) < 0.5f * x * x + dg * (1.0f - v3 + __logf(v3))) return dg * v3;
  }
  return dg;
}
__device__ inline float wave_sum(float v) {
  #pragma unroll
  for (int o = 32; o > 0; o >>= 1) v += __shfl_down(v, o, 64);
  return __shfl(v, 0, 64);
}
__device__ inline float vmf_logc(float k) {
  float k2 = k * k;
  float sm = sqrtf(65280.25f + k2);
  float sp = sqrtf(65792.25f + k2);
  return 127.75f * (logf(255.5f + sm) + logf(255.5f + sp)) - 0.5f * (sm + sp);
}
__device__ inline unsigned short f2bf(float f) {
  uint32_t u = __float_as_uint(f);
  uint32_t r = (u + 0x7FFFu + ((u >> 16) & 1u)) >> 16;
  return (unsigned short)r;
}
__device__ inline float bf2f(unsigned short s) {
  return __uint_as_float(((uint32_t)s) << 16);
}
__device__ inline void async16(const unsigned short* g, unsigned short* l) {
  __builtin_amdgcn_global_load_lds(
      (const __attribute__((address_space(1))) unsigned int*)g,
      (__attribute__((address_space(3))) unsigned int*)l, 16, 0, 0);
}

// ---------------- kernels ----------------
// prep_w: normalize class means -> bf16; per-class CUBIC Chebyshev fit of
// g(cos) = logc(kw) - logc(kk(cos)) (err ~1e-4), coeffs pre-scaled by
// log2(e) so the gemm epilogue is 3 FMA + exp2f. Also zeroes out + rowsum.
__global__ __launch_bounds__(256) void prep_w(const float* __restrict__ weight,
                                              const float* __restrict__ lscale,
                                              unsigned short* __restrict__ muWb,
                                              float4* __restrict__ cparams,
                                              float* __restrict__ rowsum,
                                              float4* __restrict__ out4) {
  __shared__ float red[4];
  int c = blockIdx.x, tid = threadIdx.x;
  if (tid < 128) out4[(size_t)c * 128 + tid] = make_float4(0.f, 0.f, 0.f, 0.f);
  if (c < 20) rowsum[c * 256 + tid] = 0.0f;   // 20*256 = 5120

  const float* wr = weight + (size_t)c * (DIMD + 2) + 1;
  float v0 = wr[tid], v1 = wr[tid + 256];
  float s = wave_sum(v0 * v0 + v1 * v1);
  if ((tid & 63) == 0) red[tid >> 6] = s;
  __syncthreads();
  float tot = red[0] + red[1] + red[2] + red[3];
  float inv = rsqrtf(tot);
  muWb[(size_t)c * DIMD + tid]       = f2bf(v0 * inv);
  muWb[(size_t)c * DIMD + tid + 256] = f2bf(v1 * inv);
  if (tid == 0) {
    float hik = weight[(size_t)c * (DIMD + 2) + DIMD + 1];
    float kw = expf(-hik);
    float k1 = expf(lscale[0]);
    float lcw = vmf_logc(kw);
    float A2 = fmaf(k1, k1, kw * kw);
    float B2 = 2.0f * k1 * kw;
    const float X0 = 0.9238795f, X1 = 0.3826834f;
    float g0 = lcw - vmf_logc(sqrtf(fmaf(B2,  X0, A2)));
    float g1 = lcw - vmf_logc(sqrtf(fmaf(B2,  X1, A2)));
    float g2 = lcw - vmf_logc(sqrtf(fmaf(B2, -X1, A2)));
    float g3 = lcw - vmf_logc(sqrtf(fmaf(B2, -X0, A2)));
    float b0 = 0.25f * (g0 + g1 + g2 + g3);
    float b1 = 0.5f * (X0 * (g0 - g3) + X1 * (g1 - g2));
    float b2 = 0.5f * 0.7071068f * ((g0 + g3) - (g1 + g2));
    float b3 = 0.5f * (X1 * (g0 - g3) - X0 * (g1 - g2));
    const float L2E = 1.4426950409f;
    cparams[c] = make_float4((b0 - b2) * L2E, (b1 - 3.0f * b3) * L2E,
                             (2.0f * b2) * L2E, (4.0f * b3) * L2E);
  }
}

// sample: 4 rows per block (1 wave per row), fused x-normalization.
// Rejection trials PARALLEL across lanes 0..31, first accepted wins.
__global__ __launch_bounds__(256) void sample_kernel(const float* __restrict__ params,
                                                     unsigned short* __restrict__ Sb) {
  int wave = threadIdx.x >> 6, lane = threadIdx.x & 63;
  int row = blockIdx.x * 4 + wave;          // b*KSAMP + k
  int b = row / KSAMP;
  const float* pr = params + (size_t)b * (DIMD + 2) + 1;

  float mu[8];
  float n2 = 0.0f;
  #pragma unroll
  for (int j = 0; j < 8; j++) { mu[j] = pr[j * 64 + lane]; n2 += mu[j] * mu[j]; }
  n2 = wave_sum(n2);
  float invn = rsqrtf(n2);
  #pragma unroll
  for (int j = 0; j < 8; j++) mu[j] *= invn;

  float kap = __expf(-pr[DIMD]);
  float bb = (-2.0f * kap + sqrtf(fmaf(4.0f * kap, kap, 511.0f * 511.0f))) / 511.0f;
  float x0 = (1.0f - bb) / (1.0f + bb);
  float cc = kap * x0 + 511.0f * __logf(1.0f - x0 * x0);

  uint64_t ctr = (((uint64_t)(row + 1)) << 32) | ((uint64_t)lane << 8);
  float g1 = gamma255(ctr);
  float g2 = gamma255(ctr);
  float z = g1 / (g1 + g2);
  float wt = (1.0f - (1.0f + bb) * z) / (1.0f - (1.0f - bb) * z);
  uint64_t r = sm64(ctr++);
  float u = u01((uint32_t)(r >> 32));
  float lhs = kap * wt + 511.0f * __logf(1.0f - x0 * wt) - cc;
  bool acc = (lane < TREJ) && (lhs >= __logf(fmaxf(u, 1e-10f)));
  uint64_t mask = __ballot(acc);
  int sel = mask ? (__ffsll((unsigned long long)mask) - 1) : 0;
  float w = __shfl(wt, sel, 64);

  uint64_t cbase = (((uint64_t)(row + 1)) << 32) | 0x40000000ull;
  float v[8];
  #pragma unroll
  for (int j = 0; j < 8; j++) v[j] = normal_from(sm64(cbase + (uint64_t)(j * 64 + lane)));
  float d = 0.0f;
  #pragma unroll
  for (int j = 0; j < 8; j++) d += v[j] * mu[j];
  d = wave_sum(d);
  float t2 = 0.0f;
  #pragma unroll
  for (int j = 0; j < 8; j++) { v[j] -= d * mu[j]; t2 += v[j] * v[j]; }
  t2 = wave_sum(t2);
  float ivt = rsqrtf(t2);
  float st = sqrtf(fmaxf(0.0f, 1.0f - w * w)) * ivt;
  float sv[8];
  float s2 = 0.0f;
  #pragma unroll
  for (int j = 0; j < 8; j++) { sv[j] = fmaf(st, v[j], w * mu[j]); s2 += sv[j] * sv[j]; }
  s2 = wave_sum(s2);
  float is = rsqrtf(s2);
  #pragma unroll
  for (int j = 0; j < 8; j++) Sb[(size_t)row * DIMD + j * 64 + lane] = f2bf(sv[j] * is);
}

// MFMA GEMM (bf16, 256x128 tile, BK=32) — R5's verified global_load_lds
// ping-pong staging (98 us) + R6's verified cubic/exp2f epilogue.
// 1-D grid with XCD stripe: xcd = id&7 owns 8 col-tiles (1 MB of W,
// L2-resident) and sweeps the 20 row-tiles.
__global__ __launch_bounds__(256, 2) void gemm_lse(const unsigned short* __restrict__ Sb,
                                                   const unsigned short* __restrict__ Wb,
                                                   const float4* __restrict__ cparams,
                                                   float* __restrict__ rowsum) {
  __shared__ __align__(16) unsigned short As[2][256 * 32];   // 2 x 16 KB
  __shared__ __align__(16) unsigned short Bs[2][128 * 32];   // 2 x 8 KB
  int tid = threadIdx.x;
  int lane = tid & 63, wave = tid >> 6;
  int tx = lane & 15, tz = lane >> 4;

  int id = blockIdx.x;                       // 64 col-tiles x 20 row-tiles = 1280
  int xcd = id & 7, lid = id >> 3;           // 160 blocks per XCD
  int c0 = (xcd * 8 + (lid & 7)) * 128;      // 8-coltile stripe per XCD
  int r0 = (lid >> 3) * 256;                 // sweep 20 row tiles

  // staging: chunk = 16 rows = 1024B (64 lanes x 16B)
  int srow = (lane >> 2);                       // 0..15 within chunk
  int kg   = (lane & 3) ^ ((lane >> 3) & 3);    // swizzled k-group (verified 0-conflict)
  int chA0 = wave * 4;                          // A: 16 chunks, 4 per wave
  int chB0 = wave * 2;                          // B: 8 chunks, 2 per wave

  f32x4 acc[4][8];
  #pragma unroll
  for (int i = 0; i < 4; i++)
    #pragma unroll
    for (int j = 0; j < 8; j++) acc[i][j] = (f32x4){0.f, 0.f, 0.f, 0.f};

  #pragma unroll
  for (int c = 0; c < 4; c++) {
    int ch = chA0 + c, rowi = ch * 16 + srow;
    async16(&Sb[(size_t)(r0 + rowi) * DIMD + kg * 8], &As[0][ch * 512]);
  }
  #pragma unroll
  for (int c = 0; c < 2; c++) {
    int ch = chB0 + c, rowi = ch * 16 + srow;
    async16(&Wb[(size_t)(c0 + rowi) * DIMD + kg * 8], &Bs[0][ch * 512]);
  }

  int p = 0;
  for (int kt = 0; kt < DIMD; kt += 32) {
    __syncthreads();   // publishes buf[p]
    if (kt + 32 < DIMD) {
      #pragma unroll
      for (int c = 0; c < 4; c++) {
        int ch = chA0 + c, rowi = ch * 16 + srow;
        async16(&Sb[(size_t)(r0 + rowi) * DIMD + kt + 32 + kg * 8], &As[p ^ 1][ch * 512]);
      }
      #pragma unroll
      for (int c = 0; c < 2; c++) {
        int ch = chB0 + c, rowi = ch * 16 + srow;
        async16(&Wb[(size_t)(c0 + rowi) * DIMD + kt + 32 + kg * 8], &Bs[p ^ 1][ch * 512]);
      }
    }
    bf16x8 af[4], bf[8];
    int sA = tz ^ ((tx >> 1) & 3);
    #pragma unroll
    for (int mi = 0; mi < 4; mi++) {
      int rA = wave * 64 + mi * 16 + tx;
      af[mi] = *(const bf16x8*)&As[p][rA * 32 + sA * 8];
    }
    #pragma unroll
    for (int ni = 0; ni < 8; ni++) {
      int rB = ni * 16 + tx;
      bf[ni] = *(const bf16x8*)&Bs[p][rB * 32 + sA * 8];
    }
    #pragma unroll
    for (int mi = 0; mi < 4; mi++)
      #pragma unroll
      for (int ni = 0; ni < 8; ni++)
        acc[mi][ni] = __builtin_amdgcn_mfma_f32_16x16x32_bf16(af[mi], bf[ni], acc[mi][ni], 0, 0, 0);
    p ^= 1;
  }

  // epilogue: s += 2^(cubic(cos)) per class
  float4 cp[8];
  #pragma unroll
  for (int ni = 0; ni < 8; ni++) cp[ni] = cparams[c0 + ni * 16 + tx];

  #pragma unroll
  for (int mi = 0; mi < 4; mi++) {
    #pragma unroll
    for (int reg = 0; reg < 4; reg++) {
      float s = 0.0f;
      #pragma unroll
      for (int ni = 0; ni < 8; ni++) {
        float cv = acc[mi][ni][reg];
        float g = fmaf(fmaf(fmaf(cp[ni].w, cv, cp[ni].z), cv, cp[ni].y), cv, cp[ni].x);
        s += exp2f(g);
      }
      #pragma unroll
      for (int o = 1; o < 16; o <<= 1) s += __shfl_xor(s, o, 64);
      if (tx == 0)
        atomicAdd(&rowsum[r0 + wave * 64 + mi * 16 + tz * 4 + reg], s);
    }
  }
}

// finalize: renormalizes mu_x from params directly
__global__ __launch_bounds__(64) void finalize_kernel(const float* __restrict__ params,
                                                      const unsigned short* __restrict__ muWb,
                                                      const float* __restrict__ rowsum,
                                                      const int* __restrict__ labels,
                                                      const float* __restrict__ lscale,
                                                      float* __restrict__ out) {
  int b = blockIdx.x;
  int lane = threadIdx.x;
  int lab = labels[b];
  const float* pr = params + (size_t)b * (DIMD + 2) + 1;
  float xv[8];
  float n2 = 0.0f;
  #pragma unroll
  for (int j = 0; j < 8; j++) { xv[j] = pr[j * 64 + lane]; n2 += xv[j] * xv[j]; }
  n2 = wave_sum(n2);
  float invn = rsqrtf(n2);
  float d = 0.0f;
  #pragma unroll
  for (int j = 0; j < 8; j++)
    d += xv[j] * invn * bf2f(muWb[(size_t)lab * DIMD + j * 64 + lane]);
  d = wave_sum(d);
  if (lane == 0) {
    float k1 = expf(lscale[0]);
    float acc = 0.0f;
    #pragma unroll
    for (int k = 0; k < KSAMP; k++) acc += __logf(rowsum[b * KSAMP + k]);
    float loss = acc * (1.0f / KSAMP) - k1 * d;
    out[(size_t)b * NCLS + lab] = -loss;
  }
}

// ---------------- launch ----------------
extern "C" void kernel_launch(void* const* d_in, const int* in_sizes, int n_in,
                              void* d_out, int out_size, void* d_ws, size_t ws_size,
                              hipStream_t stream) {
  const float* params = (const float*)d_in[0];
  const float* weight = (const float*)d_in[1];
  const float* lscale = (const float*)d_in[2];
  const int*   labels = (const int*)d_in[3];
  float* out = (float*)d_out;
  char* ws = (char*)d_ws;

  unsigned short* muWb   = (unsigned short*)(ws);                   // 8192*512*2  = 8,388,608
  unsigned short* Sb     = (unsigned short*)(ws + 8388608);         // 5120*512*2  = 5,242,880
  float4*         cparams= (float4*)(ws + 13631488);                // 8192*16     =   131,072
  float*          rowsum = (float*)(ws + 13762560);                 // 5120*4      =    20,480

  hipLaunchKernelGGL(prep_w, dim3(NCLS), dim3(256), 0, stream,
                     weight, lscale, muWb, cparams, rowsum, (float4*)out);
  hipLaunchKernelGGL(sample_kernel, dim3(BATCH * KSAMP / 4), dim3(256), 0, stream,
                     params, Sb);
  hipLaunchKernelGGL(gemm_lse, dim3((NCLS / 128) * (BATCH * KSAMP / 256)), dim3(256), 0, stream,
                     Sb, muWb, cparams, rowsum);
  hipLaunchKernelGGL(finalize_kernel, dim3(BATCH), dim3(64), 0, stream,
                     params, muWb, rowsum, labels, lscale, out);
}

// Round 9
// 168.204 us; speedup vs baseline: 1.8140x; 1.0044x over previous
//
#include <hip/hip_runtime.h>
#include <stdint.h>

#define DIMD 512
#define BATCH 512
#define KSAMP 10
#define NCLS 8192
#define TREJ 32

typedef __bf16 bf16x8 __attribute__((ext_vector_type(8)));
typedef float f32x4 __attribute__((ext_vector_type(4)));

// ---------------- RNG (counter-based, deterministic) ----------------
__device__ inline uint64_t sm64(uint64_t x) {
  x += 0x9E3779B97F4A7C15ull;
  x = (x ^ (x >> 30)) * 0xBF58476D1CE4E5B9ull;
  x = (x ^ (x >> 27)) * 0x94D049BB133111EBull;
  return x ^ (x >> 31);
}
__device__ inline float u01(uint32_t u) {
  return ((float)u + 0.5f) * 2.3283064365386963e-10f;
}
__device__ inline float normal_from(uint64_t r) {
  float u1 = u01((uint32_t)(r >> 32));
  float u2 = u01((uint32_t)r);
  return sqrtf(-2.0f * __logf(u1)) * __cosf(6.28318530718f * u2);
}
__device__ inline float gamma255(uint64_t& ctr) {
  const float dg = 255.1666667f;
  const float cg = 0.02086730f;
  for (int i = 0; i < 16; i++) {
    uint64_t r = sm64(ctr++);
    float x = normal_from(r);
    float t = fmaf(cg, x, 1.0f);
    if (t <= 0.0f) continue;
    float v3 = t * t * t;
    uint64_t r2 = sm64(ctr++);
    float u3 = u01((uint32_t)(r2 >> 32));
    if (__logf(u3) < 0.5f * x * x + dg * (1.0f - v3 + __logf(v3))) return dg * v3;
  }
  return dg;
}
__device__ inline float wave_sum(float v) {
  #pragma unroll
  for (int o = 32; o > 0; o >>= 1) v += __shfl_down(v, o, 64);
  return __shfl(v, 0, 64);
}
__device__ inline float vmf_logc(float k) {
  float k2 = k * k;
  float sm = sqrtf(65280.25f + k2);
  float sp = sqrtf(65792.25f + k2);
  return 127.75f * (logf(255.5f + sm) + logf(255.5f + sp)) - 0.5f * (sm + sp);
}
__device__ inline unsigned short f2bf(float f) {
  uint32_t u = __float_as_uint(f);
  uint32_t r = (u + 0x7FFFu + ((u >> 16) & 1u)) >> 16;
  return (unsigned short)r;
}
__device__ inline float bf2f(unsigned short s) {
  return __uint_as_float(((uint32_t)s) << 16);
}
// CK-style lightweight barrier: drains LDS ops only; buffer_loads (VGPR
// destinations, wave-private) legitimately stay in flight across it.
__device__ inline void sync_lds() {
  asm volatile("s_waitcnt lgkmcnt(0)\n\ts_barrier" ::: "memory");
}

// ---------- fused prep (blocks 0..2047, one WAVE per class) + sample ----------
__global__ __launch_bounds__(256) void prep_sample(const float* __restrict__ weight,
                                                   const float* __restrict__ params,
                                                   const float* __restrict__ lscale,
                                                   unsigned short* __restrict__ muWb,
                                                   float4* __restrict__ cparams,
                                                   float* __restrict__ rowsum,
                                                   float4* __restrict__ out4,
                                                   unsigned short* __restrict__ Sb) {
  int blk = blockIdx.x, tid = threadIdx.x;
  int wave = tid >> 6, lane = tid & 63;
  if (blk < 2048) {
    // zero out: 2048 blocks x 512 float4 = exactly 512x8192 fp32
    out4[(size_t)blk * 512 + tid]       = make_float4(0.f, 0.f, 0.f, 0.f);
    out4[(size_t)blk * 512 + 256 + tid] = make_float4(0.f, 0.f, 0.f, 0.f);
    if (blk < 20) rowsum[blk * 256 + tid] = 0.0f;   // 20*256 = 5120

    int c = blk * 4 + wave;                 // one wave per class, no barriers
    const float* wr = weight + (size_t)c * (DIMD + 2) + 1;
    float v[8];
    float n2 = 0.0f;
    #pragma unroll
    for (int j = 0; j < 8; j++) { v[j] = wr[j * 64 + lane]; n2 += v[j] * v[j]; }
    n2 = wave_sum(n2);
    float inv = rsqrtf(n2);
    #pragma unroll
    for (int j = 0; j < 8; j++)
      muWb[(size_t)c * DIMD + j * 64 + lane] = f2bf(v[j] * inv);

    // cubic Chebyshev fit of g(cos)=logc(kw)-logc(kk(cos)); nodes on lanes 0-3
    float hik = wr[DIMD];                   // col 513
    float kw = expf(-hik);
    float k1 = expf(lscale[0]);
    float lcw = vmf_logc(kw);
    float A2 = fmaf(k1, k1, kw * kw);
    float B2 = 2.0f * k1 * kw;
    const float X0 = 0.9238795f, X1 = 0.3826834f;
    int l3 = lane & 3;
    float Xj = (l3 == 0) ? X0 : (l3 == 1) ? X1 : (l3 == 2) ? -X1 : -X0;
    float gj = lcw - vmf_logc(sqrtf(fmaf(B2, Xj, A2)));
    float g0 = __shfl(gj, 0, 64), g1 = __shfl(gj, 1, 64);
    float g2 = __shfl(gj, 2, 64), g3 = __shfl(gj, 3, 64);
    if (lane == 0) {
      float b0 = 0.25f * (g0 + g1 + g2 + g3);
      float b1 = 0.5f * (X0 * (g0 - g3) + X1 * (g1 - g2));
      float b2 = 0.5f * 0.7071068f * ((g0 + g3) - (g1 + g2));
      float b3 = 0.5f * (X1 * (g0 - g3) - X0 * (g1 - g2));
      const float L2E = 1.4426950409f;
      cparams[c] = make_float4((b0 - b2) * L2E, (b1 - 3.0f * b3) * L2E,
                               (2.0f * b2) * L2E, (4.0f * b3) * L2E);
    }
  } else {
    // sample: 1 wave per row; rejection trials parallel across lanes 0..31
    int row = (blk - 2048) * 4 + wave;      // b*KSAMP + k
    int b = row / KSAMP;
    const float* pr = params + (size_t)b * (DIMD + 2) + 1;

    float mu[8];
    float n2 = 0.0f;
    #pragma unroll
    for (int j = 0; j < 8; j++) { mu[j] = pr[j * 64 + lane]; n2 += mu[j] * mu[j]; }
    n2 = wave_sum(n2);
    float invn = rsqrtf(n2);
    #pragma unroll
    for (int j = 0; j < 8; j++) mu[j] *= invn;

    float kap = __expf(-pr[DIMD]);
    float bb = (-2.0f * kap + sqrtf(fmaf(4.0f * kap, kap, 511.0f * 511.0f))) / 511.0f;
    float x0 = (1.0f - bb) / (1.0f + bb);
    float cc = kap * x0 + 511.0f * __logf(1.0f - x0 * x0);

    uint64_t ctr = (((uint64_t)(row + 1)) << 32) | ((uint64_t)lane << 8);
    float g1 = gamma255(ctr);
    float g2 = gamma255(ctr);
    float z = g1 / (g1 + g2);
    float wt = (1.0f - (1.0f + bb) * z) / (1.0f - (1.0f - bb) * z);
    uint64_t r = sm64(ctr++);
    float u = u01((uint32_t)(r >> 32));
    float lhs = kap * wt + 511.0f * __logf(1.0f - x0 * wt) - cc;
    bool acc = (lane < TREJ) && (lhs >= __logf(fmaxf(u, 1e-10f)));
    uint64_t mask = __ballot(acc);
    int sel = mask ? (__ffsll((unsigned long long)mask) - 1) : 0;
    float w = __shfl(wt, sel, 64);

    uint64_t cbase = (((uint64_t)(row + 1)) << 32) | 0x40000000ull;
    float v[8];
    #pragma unroll
    for (int j = 0; j < 8; j++) v[j] = normal_from(sm64(cbase + (uint64_t)(j * 64 + lane)));
    float d = 0.0f;
    #pragma unroll
    for (int j = 0; j < 8; j++) d += v[j] * mu[j];
    d = wave_sum(d);
    float t2 = 0.0f;
    #pragma unroll
    for (int j = 0; j < 8; j++) { v[j] -= d * mu[j]; t2 += v[j] * v[j]; }
    t2 = wave_sum(t2);
    float ivt = rsqrtf(t2);
    float st = sqrtf(fmaxf(0.0f, 1.0f - w * w)) * ivt;
    float sv[8];
    float s2 = 0.0f;
    #pragma unroll
    for (int j = 0; j < 8; j++) { sv[j] = fmaf(st, v[j], w * mu[j]); s2 += sv[j] * sv[j]; }
    s2 = wave_sum(s2);
    float is = rsqrtf(s2);
    #pragma unroll
    for (int j = 0; j < 8; j++) Sb[(size_t)row * DIMD + j * 64 + lane] = f2bf(sv[j] * is);
  }
}

// MFMA GEMM (bf16, 128x128, BK=32). AITER-style K-loop, FULLY UNROLLED:
// buffer_load -> named VGPR sets (static indices only; R7's scratch fix) ->
// ds_write (async16's verified lane map: row=lane>>2, slot=lane&3,
// kg=(lane&3)^((lane>>3)&3); 2-way max = free) -> lightweight lgkm-only
// barrier, so prefetch loads stay in flight ACROSS barriers (vmcnt never 0).
__global__ __launch_bounds__(256, 3) void gemm_lse(const unsigned short* __restrict__ Sb,
                                                   const unsigned short* __restrict__ Wb,
                                                   const float4* __restrict__ cparams,
                                                   float* __restrict__ rowsum) {
  __shared__ __align__(16) unsigned short As[2][128 * 32];
  __shared__ __align__(16) unsigned short Bs[2][128 * 32];
  int tid = threadIdx.x;
  int lane = tid & 63, wave = tid >> 6;
  int wm = wave >> 1, wn = wave & 1;
  int tx = lane & 15, tz = lane >> 4;

  int id = blockIdx.x;                       // 64 col-tiles x 40 row-tiles = 2560
  int xcd = id & 7, lid = id >> 3;           // 320 blocks per XCD
  int c0 = (xcd * 8 + (lid & 7)) * 128;      // 8-coltile stripe per XCD (1 MB W in L2)
  int r0 = (lid >> 3) * 128;                 // sweep 40 row tiles

  int kg = (lane & 3) ^ ((lane >> 3) & 3);   // global k-group this lane stages
  int srow = wave * 32 + (lane >> 2);        // staged row (lo chunk); hi = +16
  const unsigned short* gA0 = Sb + (size_t)(r0 + srow) * DIMD + kg * 8;
  const unsigned short* gA1 = gA0 + 16 * DIMD;
  const unsigned short* gB0 = Wb + (size_t)(c0 + srow) * DIMD + kg * 8;
  const unsigned short* gB1 = gB0 + 16 * DIMD;
  int ldsA = srow * 32 + (lane & 3) * 8;     // slot lane&3 holds k-group kg

  f32x4 acc[4][4];
  #pragma unroll
  for (int i = 0; i < 4; i++)
    #pragma unroll
    for (int j = 0; j < 4; j++) acc[i][j] = (f32x4){0.f, 0.f, 0.f, 0.f};

  int4 a0lo, a0hi, b0lo, b0hi;   // set 0: even chunks
  int4 a1lo, a1hi, b1lo, b1hi;   // set 1: odd chunks

#define LOADCH(CI, ALO, AHI, BLO, BHI)                      \
  { ALO = *(const int4*)(gA0 + (CI) * 32);                  \
    AHI = *(const int4*)(gA1 + (CI) * 32);                  \
    BLO = *(const int4*)(gB0 + (CI) * 32);                  \
    BHI = *(const int4*)(gB1 + (CI) * 32); }

#define WRITELDS(P, ALO, AHI, BLO, BHI)                     \
  { *(int4*)&As[P][ldsA]       = ALO;                       \
    *(int4*)&As[P][ldsA + 512] = AHI;                       \
    *(int4*)&Bs[P][ldsA]       = BLO;                       \
    *(int4*)&Bs[P][ldsA + 512] = BHI; }

#define COMPUTE(P)                                          \
  { bf16x8 af[4], bf[4];                                    \
    int sA_ = tz ^ ((tx >> 1) & 3);                         \
    _Pragma("unroll")                                       \
    for (int mi = 0; mi < 4; mi++) {                        \
      af[mi] = *(const bf16x8*)&As[P][(wm * 64 + mi * 16 + tx) * 32 + sA_ * 8]; \
      bf[mi] = *(const bf16x8*)&Bs[P][(wn * 64 + mi * 16 + tx) * 32 + sA_ * 8]; \
    }                                                       \
    _Pragma("unroll")                                       \
    for (int mi = 0; mi < 4; mi++)                          \
      _Pragma("unroll")                                     \
      for (int ni = 0; ni < 4; ni++)                        \
        acc[mi][ni] = __builtin_amdgcn_mfma_f32_16x16x32_bf16(af[mi], bf[ni], acc[mi][ni], 0, 0, 0); }

  // prologue: chunks 0,1 in flight; publish chunk 0
  LOADCH(0, a0lo, a0hi, b0lo, b0hi);
  LOADCH(1, a1lo, a1hi, b1lo, b1hi);
  WRITELDS(0, a0lo, a0hi, b0lo, b0hi);
  sync_lds();

#define GITER_EVEN(IT)                                      \
  { if ((IT) + 2 < 16) LOADCH((IT) + 2, a0lo, a0hi, b0lo, b0hi); \
    COMPUTE(0);                                             \
    if ((IT) + 1 < 16) WRITELDS(1, a1lo, a1hi, b1lo, b1hi); \
    if ((IT) < 15) sync_lds(); }

#define GITER_ODD(IT)                                       \
  { if ((IT) + 2 < 16) LOADCH((IT) + 2, a1lo, a1hi, b1lo, b1hi); \
    COMPUTE(1);                                             \
    if ((IT) + 1 < 16) WRITELDS(0, a0lo, a0hi, b0lo, b0hi); \
    if ((IT) < 15) sync_lds(); }

  GITER_EVEN(0)  GITER_ODD(1)  GITER_EVEN(2)  GITER_ODD(3)
  GITER_EVEN(4)  GITER_ODD(5)  GITER_EVEN(6)  GITER_ODD(7)
  GITER_EVEN(8)  GITER_ODD(9)  GITER_EVEN(10) GITER_ODD(11)
  GITER_EVEN(12) GITER_ODD(13) GITER_EVEN(14) GITER_ODD(15)

  // epilogue: s += 2^(cubic(cos)) per class
  float4 cp[4];
  #pragma unroll
  for (int ni = 0; ni < 4; ni++) cp[ni] = cparams[c0 + wn * 64 + ni * 16 + tx];

  #pragma unroll
  for (int mi = 0; mi < 4; mi++) {
    #pragma unroll
    for (int reg = 0; reg < 4; reg++) {
      float s = 0.0f;
      #pragma unroll
      for (int ni = 0; ni < 4; ni++) {
        float cv = acc[mi][ni][reg];
        float g = fmaf(fmaf(fmaf(cp[ni].w, cv, cp[ni].z), cv, cp[ni].y), cv, cp[ni].x);
        s += exp2f(g);
      }
      #pragma unroll
      for (int o = 1; o < 16; o <<= 1) s += __shfl_xor(s, o, 64);
      if (tx == 0)
        atomicAdd(&rowsum[r0 + wm * 64 + mi * 16 + tz * 4 + reg], s);
    }
  }
}

// finalize: renormalizes mu_x from params directly
__global__ __launch_bounds__(64) void finalize_kernel(const float* __restrict__ params,
                                                      const unsigned short* __restrict__ muWb,
                                                      const float* __restrict__ rowsum,
                                                      const int* __restrict__ labels,
                                                      const float* __restrict__ lscale,
                                                      float* __restrict__ out) {
  int b = blockIdx.x;
  int lane = threadIdx.x;
  int lab = labels[b];
  const float* pr = params + (size_t)b * (DIMD + 2) + 1;
  float xv[8];
  float n2 = 0.0f;
  #pragma unroll
  for (int j = 0; j < 8; j++) { xv[j] = pr[j * 64 + lane]; n2 += xv[j] * xv[j]; }
  n2 = wave_sum(n2);
  float invn = rsqrtf(n2);
  float d = 0.0f;
  #pragma unroll
  for (int j = 0; j < 8; j++)
    d += xv[j] * invn * bf2f(muWb[(size_t)lab * DIMD + j * 64 + lane]);
  d = wave_sum(d);
  if (lane == 0) {
    float k1 = expf(lscale[0]);
    float acc = 0.0f;
    #pragma unroll
    for (int k = 0; k < KSAMP; k++) acc += __logf(rowsum[b * KSAMP + k]);
    float loss = acc * (1.0f / KSAMP) - k1 * d;
    out[(size_t)b * NCLS + lab] = -loss;
  }
}

// ---------------- launch ----------------
extern "C" void kernel_launch(void* const* d_in, const int* in_sizes, int n_in,
                              void* d_out, int out_size, void* d_ws, size_t ws_size,
                              hipStream_t stream) {
  const float* params = (const float*)d_in[0];
  const float* weight = (const float*)d_in[1];
  const float* lscale = (const float*)d_in[2];
  const int*   labels = (const int*)d_in[3];
  float* out = (float*)d_out;
  char* ws = (char*)d_ws;

  unsigned short* muWb   = (unsigned short*)(ws);                   // 8192*512*2  = 8,388,608
  unsigned short* Sb     = (unsigned short*)(ws + 8388608);         // 5120*512*2  = 5,242,880
  float4*         cparams= (float4*)(ws + 13631488);                // 8192*16     =   131,072
  float*          rowsum = (float*)(ws + 13762560);                 // 5120*4      =    20,480

  hipLaunchKernelGGL(prep_sample, dim3(2048 + BATCH * KSAMP / 4), dim3(256), 0, stream,
                     weight, params, lscale, muWb, cparams, rowsum, (float4*)out, Sb);
  hipLaunchKernelGGL(gemm_lse, dim3((NCLS / 128) * (BATCH * KSAMP / 128)), dim3(256), 0, stream,
                     Sb, muWb, cparams, rowsum);
  hipLaunchKernelGGL(finalize_kernel, dim3(BATCH), dim3(64), 0, stream,
                     params, muWb, rowsum, labels, lscale, out);
}